// Round 6
// baseline (1125.965 us; speedup 1.0000x reference)
//
#include <hip/hip_runtime.h>
#include <hip/hip_bf16.h>
#include <cstdint>
#include <cstddef>

#define B_  8
#define S_  1300
#define D_  1080
#define H_  12
#define DK_ 90
#define FF_ 3240
#define MROWS (B_*S_)   // 10400
#define KP1 1088        // 1080 padded to /32
#define KP2 3264        // 3240 padded to /32
#define SP  1312        // S padded to /32 (41 K-tiles)
#define QKVN 3240       // 3*D
#define QSCALE 0.105409255338946f   // 1/sqrt(90)

typedef __hip_bfloat16 bf16;
typedef __bf16 bf16x8 __attribute__((ext_vector_type(8)));
typedef float  f32x4  __attribute__((ext_vector_type(4)));
typedef unsigned short u16x8 __attribute__((ext_vector_type(8)));
typedef unsigned int   u32x4 __attribute__((ext_vector_type(4)));

__device__ __forceinline__ void gload16(const void* g, void* l) {
    __builtin_amdgcn_global_load_lds((const __attribute__((address_space(1))) void*)g,
                                     (__attribute__((address_space(3))) void*)l, 16, 0, 0);
}
__device__ __forceinline__ unsigned short bf16bits(float f) {
    bf16 b = __float2bfloat16(f);
    return *(unsigned short*)&b;
}
// inline-asm LDS read: invisible to hipcc's waitcnt pass, so the outstanding
// global_load_lds ops are NOT auto-drained before it (the counted-vmcnt enabler).
// Rule 18: must be followed by s_waitcnt lgkmcnt(0) + sched_barrier(0) before use.
__device__ __forceinline__ bf16x8 dsr(unsigned byteaddr) {
    union { u32x4 u; bf16x8 b; } c;
    asm volatile("ds_read_b128 %0, %1" : "=&v"(c.u) : "v"(byteaddr));
    return c.b;
}

#define BAR()   __builtin_amdgcn_s_barrier()
#define LGKM0() asm volatile("s_waitcnt lgkmcnt(0)" ::: "memory")
#define SCB()   __builtin_amdgcn_sched_barrier(0)

// ================== zero pad columns [D_, KP1) of bf16 [MROWS, KP1] ==================
__global__ __launch_bounds__(256) void zero_pads(bf16* __restrict__ buf)
{
    const int idx = blockIdx.x * 256 + threadIdx.x;
    if (idx >= MROWS * (KP1 - D_)) return;
    const int row = idx >> 3, col = D_ + (idx & 7);
    buf[(size_t)row * KP1 + col] = __float2bfloat16(0.f);
}

// ================== concat qkv bias ==================
__global__ __launch_bounds__(256) void bcat(const float* __restrict__ bq,
    const float* __restrict__ bk, const float* __restrict__ bv,
    float* __restrict__ bqkv)
{
    const int i = blockIdx.x * 256 + threadIdx.x;
    if (i >= QKVN) return;
    bqkv[i] = (i < D_) ? bq[i] : (i < 2 * D_) ? bk[i - D_] : bv[i - 2 * D_];
}

// ===================== weight cast + transpose =====================
__global__ __launch_bounds__(256) void castT(const float* __restrict__ W,
    bf16* __restrict__ WT, int K, int N, int KP)
{
    __shared__ unsigned short t[32][33];
    const int tx = threadIdx.x & 31, ty = threadIdx.x >> 5;
    const int k0 = blockIdx.x * 32, n0 = blockIdx.y * 32;
    #pragma unroll
    for (int i = 0; i < 4; ++i) {
        const int k = k0 + ty + 8 * i;
        const int n = n0 + tx;
        float v = (k < K && n < N) ? W[(size_t)k * N + n] : 0.f;
        t[ty + 8 * i][tx] = bf16bits(v);
    }
    __syncthreads();
    #pragma unroll
    for (int i = 0; i < 4; ++i) {
        const int n = n0 + ty + 8 * i;
        const int kk = k0 + tx;
        if (n < N && kk < KP) *(unsigned short*)&WT[(size_t)n * KP + kk] = t[tx][ty + 8 * i];
    }
}

// ============================= LayerNorm =============================
__global__ __launch_bounds__(256) void ln_kernel(const float* __restrict__ x,
    const float* __restrict__ g, const float* __restrict__ b,
    bf16* __restrict__ y)
{
    __shared__ float xs[D_];
    __shared__ float red[8];
    const int row = blockIdx.x;
    const int tid = threadIdx.x;
    const float* xr = x + (size_t)row * D_;

    float s = 0.f, sq = 0.f;
    for (int d = tid; d < D_; d += 256) {
        float v = xr[d];
        xs[d] = v;
        s += v; sq += v * v;
    }
    #pragma unroll
    for (int off = 32; off > 0; off >>= 1) {
        s  += __shfl_down(s,  off, 64);
        sq += __shfl_down(sq, off, 64);
    }
    const int wave = tid >> 6, lane = tid & 63;
    if (lane == 0) { red[wave] = s; red[4 + wave] = sq; }
    __syncthreads();
    if (tid == 0) {
        float ts = 0.f, tq = 0.f;
        #pragma unroll
        for (int w = 0; w < 4; ++w) { ts += red[w]; tq += red[4 + w]; }
        red[0] = ts; red[4] = tq;
    }
    __syncthreads();
    const float mean = red[0] * (1.0f / D_);
    const float var  = red[4] * (1.0f / D_) - mean * mean;
    const float rstd = rsqrtf(var + 1e-5f);
    bf16* yr = y + (size_t)row * KP1;
    for (int d = tid; d < D_; d += 256)
        yr[d] = __float2bfloat16((xs[d] - mean) * rstd * g[d] + b[d]);
}

// ============================= bf16 MFMA GEMM (128x128, counted-vmcnt 3-slot ring) =============================
// (unchanged from round 5 - verified improvement: all GEMMs dropped below attn's 181 us)
template<int MODE>
__global__ __launch_bounds__(256, 3) void gemm_bf16(
    const bf16* __restrict__ A, const bf16* __restrict__ BT,
    const float* __restrict__ bias, const float* __restrict__ res,
    float* __restrict__ Cf, bf16* __restrict__ Cb,
    int M, int N, int KP, int LDC, int NP)
{
    __shared__ unsigned short lds[24576];   // 48 KB: A slots [0,12288), B slots [12288,24576)

    const int tid = threadIdx.x;
    const int w = tid >> 6, l = tid & 63;
    const int lr = l & 15, kq = l >> 4;
    const int m0 = blockIdx.y * 128, n0 = blockIdx.x * 128;

    const int rs = w * 16 + (l >> 2);
    const int sx = ((l & 3) ^ ((l >> 3) & 3)) * 8;   // shorts
    const int ar0 = min(m0 + rs,      M - 1);
    const int ar1 = min(m0 + rs + 64, M - 1);
    const int br0 = min(n0 + rs,      N - 1);
    const int br1 = min(n0 + rs + 64, N - 1);
    const bf16* pa0 = A  + (size_t)ar0 * KP + sx;
    const bf16* pa1 = A  + (size_t)ar1 * KP + sx;
    const bf16* pb0 = BT + (size_t)br0 * KP + sx;
    const bf16* pb1 = BT + (size_t)br1 * KP + sx;

    const int wm = (w >> 1) * 64, wn = (w & 1) * 64;

    const unsigned ldsb = (unsigned)(size_t)(const __attribute__((address_space(3))) void*)&lds[0];
    const unsigned co = (unsigned)((kq ^ ((lr >> 1) & 3)) << 4);   // bytes
    unsigned aoffB[4], boffB[4];
    #pragma unroll
    for (int i = 0; i < 4; ++i) {
        aoffB[i] = ldsb + (unsigned)((wm + i * 16 + lr) * 64) + co;
        boffB[i] = ldsb + 24576u + (unsigned)((wn + i * 16 + lr) * 64) + co;
    }

    f32x4 acc[4][4] = {};
    const int nkt = KP >> 5;

#define STAGE(t, sl) do { \
    gload16(pa0 + (size_t)(t) * 32, &lds[(sl) * 4096 + w * 512]); \
    gload16(pa1 + (size_t)(t) * 32, &lds[(sl) * 4096 + 2048 + w * 512]); \
    gload16(pb0 + (size_t)(t) * 32, &lds[12288 + (sl) * 4096 + w * 512]); \
    gload16(pb1 + (size_t)(t) * 32, &lds[12288 + (sl) * 4096 + 2048 + w * 512]); \
} while (0)

    STAGE(0, 0);
    STAGE(1, 1);

    int sc_ = 0;
    int ss_ = 2;
    for (int t = 0; t < nkt; ++t) {
        if (t + 1 < nkt) { asm volatile("s_waitcnt vmcnt(4)" ::: "memory"); }
        else             { asm volatile("s_waitcnt vmcnt(0)" ::: "memory"); }
        BAR(); SCB();
        if (t + 2 < nkt) STAGE(t + 2, ss_);

        const unsigned sb = (unsigned)(sc_ * 8192);
        bf16x8 af[4], bv[4];
        #pragma unroll
        for (int i = 0; i < 4; ++i) af[i] = dsr(aoffB[i] + sb);
        #pragma unroll
        for (int j = 0; j < 4; ++j) bv[j] = dsr(boffB[j] + sb);
        LGKM0(); SCB();
        #pragma unroll
        for (int i = 0; i < 4; ++i)
            #pragma unroll
            for (int j = 0; j < 4; ++j)
                acc[i][j] = __builtin_amdgcn_mfma_f32_16x16x32_bf16(af[i], bv[j], acc[i][j], 0, 0, 0);
        SCB();

        sc_ = (sc_ == 2) ? 0 : sc_ + 1;
        ss_ = (ss_ == 2) ? 0 : ss_ + 1;
    }
#undef STAGE

    // ===== epilogue =====
    #pragma unroll
    for (int j = 0; j < 4; ++j) {
        const int n = n0 + wn + j * 16 + lr;
        if (n >= NP) continue;
        const bool real = (n < N);
        const float bn = real ? bias[n] : 0.f;
        #pragma unroll
        for (int i = 0; i < 4; ++i) {
            const int rowb = m0 + wm + i * 16 + kq * 4;
            #pragma unroll
            for (int r = 0; r < 4; ++r) {
                const int m = rowb + r;
                if (m < M) {
                    const size_t off = (size_t)m * LDC + n;
                    float val = acc[i][j][r] + bn;
                    if (MODE == 0) Cf[off] = val;
                    if (MODE == 1) Cf[off] = val + res[off];
                    if (MODE == 3) Cb[off] = real ? __float2bfloat16(val) : __float2bfloat16(0.f);
                    if (MODE == 2) {
                        if (real) {
                            const float prev = __bfloat162float(Cb[off]);
                            const float sig  = 1.0f / (1.0f + __expf(-prev));
                            Cb[off] = __float2bfloat16(prev * sig * val);
                        } else {
                            Cb[off] = __float2bfloat16(0.f);
                        }
                    }
                }
            }
        }
    }
}

// ============================= RoPE + head layout (bf16 qkv -> bf16 Qa/Ka) =============================
__global__ __launch_bounds__(256) void rope_qk(const bf16* __restrict__ qkv,
    const float* __restrict__ cosb, const float* __restrict__ sinb,
    bf16* __restrict__ Qa, bf16* __restrict__ Ka)
{
    const int s = blockIdx.x;       // 0..SP-1
    const int b = blockIdx.y;
    const int tid = threadIdx.x;

    if (s >= S_) {
        for (int idx = tid; idx < H_ * 96; idx += 256) {
            const int h = idx / 96, c = idx - (idx / 96) * 96;
            const size_t o = ((size_t)(b * H_ + h) * SP + s) * 96 + c;
            Qa[o] = __float2bfloat16(0.f);
            Ka[o] = __float2bfloat16(0.f);
        }
        return;
    }

    const bf16* row = qkv + (size_t)(b * S_ + s) * QKVN;

    for (int idx = tid; idx < H_ * 45; idx += 256) {
        const int h = idx / 45, d = idx - (idx / 45) * 45;
        const float c1 = cosb[s * DK_ + d],      s1 = sinb[s * DK_ + d];
        const float c2 = cosb[s * DK_ + d + 45], s2 = sinb[s * DK_ + d + 45];
        const size_t o = ((size_t)(b * H_ + h) * SP + s) * 96;
        const float q1 = __bfloat162float(row[h * DK_ + d]);
        const float q2 = __bfloat162float(row[h * DK_ + d + 45]);
        Qa[o + d]      = __float2bfloat16((q1 * c1 - q2 * s1) * QSCALE);
        Qa[o + d + 45] = __float2bfloat16((q2 * c2 + q1 * s2) * QSCALE);
        const float k1 = __bfloat162float(row[D_ + h * DK_ + d]);
        const float k2 = __bfloat162float(row[D_ + h * DK_ + d + 45]);
        Ka[o + d]      = __float2bfloat16(k1 * c1 - k2 * s1);
        Ka[o + d + 45] = __float2bfloat16(k2 * c2 + k1 * s2);
    }
    for (int idx = tid; idx < H_ * 6; idx += 256) {
        const int h = idx / 6, c = 90 + (idx - (idx / 6) * 6);
        const size_t o = ((size_t)(b * H_ + h) * SP + s) * 96 + c;
        Qa[o] = __float2bfloat16(0.f);
        Ka[o] = __float2bfloat16(0.f);
    }
}

// ============================= V transpose (bf16 qkv -> bf16 Vt) =============================
// v section of qkv -> Vt bf16 [B*H][96][SP]
__global__ __launch_bounds__(256) void vtrans(const bf16* __restrict__ qkv,
    bf16* __restrict__ Vt)
{
    __shared__ float T[96][33];
    const int k0 = blockIdx.x * 32;
    const int bh = blockIdx.y;
    const int b = bh / H_, h = bh % H_;
    const int tid = threadIdx.x;

    for (int idx = tid; idx < 32 * 90; idx += 256) {
        const int r = idx / 90, d = idx - (idx / 90) * 90;
        const int s = k0 + r;
        T[d][r] = (s < S_) ?
            __bfloat162float(qkv[(size_t)(b * S_ + s) * QKVN + 2 * D_ + h * DK_ + d]) : 0.f;
    }
    for (int idx = tid; idx < 32 * 6; idx += 256) {
        const int r = idx / 6, d = 90 + (idx - (idx / 6) * 6);
        T[d][r] = 0.f;
    }
    __syncthreads();
    for (int idx = tid; idx < 96 * 4; idx += 256) {
        const int d = idx >> 2, kk = (idx & 3) * 8;
        u16x8 v;
        #pragma unroll
        for (int i = 0; i < 8; ++i) v[i] = bf16bits(T[d][kk + i]);
        *(u16x8*)(Vt + ((size_t)bh * 96 + d) * SP + k0 + kk) = v;
    }
}

// ============================= MFMA flash attention (128 q/block, 2 frags/wave) =============================
// grid (11, B*H), 256 thr = 4 waves. 128 queries/block (32/wave via 2 Q-fragments),
// KV tile = 32. Tile count per head: 261 vs 462 at 64-q blocks (-43% per-tile overhead).
// Interior tiles (k0+31 <= qw0, wave-uniform) skip all causal masks.
// exp guard removed: tile 0 always has an unmasked key per valid query, so the running
// max is real before any fully-masked thread-slot can contribute exp(0).
__global__ __launch_bounds__(256) void attn_mfma(const bf16* __restrict__ Qa,
    const bf16* __restrict__ Ka, const bf16* __restrict__ Vt,
    bf16* __restrict__ ab)
{
    __shared__ unsigned short Qs[128][104];  // 26624 B
    __shared__ unsigned short Ks[32][104];   //  6656 B
    __shared__ unsigned short Vs[96][40];    //  7680 B
    __shared__ unsigned short Ps[4][32][40]; // 10240 B   total 51200 B -> 3 blocks/CU

    const int tid = threadIdx.x;
    const int w = tid >> 6, l = tid & 63;
    const int lr = l & 15, kq = l >> 4;
    const int qblk = (int)gridDim.x - 1 - (int)blockIdx.x;   // big blocks first
    const int q0 = qblk * 128;
    const int bh = blockIdx.y;
    const int b = bh / H_, h = bh % H_;

    const bf16* Qg = Qa + (size_t)bh * SP * 96;
    const bf16* Kg = Ka + (size_t)bh * SP * 96;
    const bf16* Vg = Vt + (size_t)bh * 96 * SP;

    // ---- stage Q (128 rows x 96 cols) ----
    for (int c = tid; c < 1536; c += 256) {
        const int row = c / 12, cc = c - row * 12;
        const int rg = q0 + row;
        u16x8 v = (u16x8)0;
        if (rg < SP) v = *(const u16x8*)(Qg + (size_t)rg * 96 + cc * 8);
        *(u16x8*)&Qs[row][cc * 8] = v;
    }
    __syncthreads();

    bf16x8 Qf[2][3];
    #pragma unroll
    for (int f = 0; f < 2; ++f)
        #pragma unroll
        for (int kf = 0; kf < 3; ++kf)
            Qf[f][kf] = *(const bf16x8*)&Qs[w * 32 + f * 16 + lr][kf * 32 + kq * 8];

    const int qw0 = q0 + w * 32;
    const int myq0 = qw0 + lr;
    const int myq1 = qw0 + 16 + lr;
    const int wlq = (qw0 < S_) ? min(qw0 + 31, S_ - 1) : -1;
    const int lastq = min(q0 + 127, S_ - 1);
    const int ntiles = lastq / 32 + 1;

    f32x4 Of[2][6] = {};
    float mr0 = -1e30f, lr0_ = 0.f;
    float mr1 = -1e30f, lr1_ = 0.f;

    for (int kt = 0; kt < ntiles; ++kt) {
        const int k0 = kt * 32;
        __syncthreads();
        // stage K tile (32 rows x 96 cols)
        for (int c = tid; c < 384; c += 256) {
            const int row = c / 12, cc = c - (c / 12) * 12;
            *(u16x8*)&Ks[row][cc * 8] = *(const u16x8*)(Kg + (size_t)(k0 + row) * 96 + cc * 8);
        }
        // stage V tile (96 dims x 32 keys)
        for (int c = tid; c < 384; c += 256) {
            const int d = c >> 2, kk = (c & 3) * 8;
            *(u16x8*)&Vs[d][kk] = *(const u16x8*)(Vg + (size_t)d * SP + k0 + kk);
        }
        __syncthreads();

        if (k0 > wlq) continue;   // wave-uniform skip; barriers above still executed

        // ---- S^T = K Q^T : sg[f][g][r] = S[key k0+16g+4kq+r][query qw0+16f+lr] ----
        f32x4 sg00 = {0,0,0,0}, sg01 = {0,0,0,0}, sg10 = {0,0,0,0}, sg11 = {0,0,0,0};
        #pragma unroll
        for (int kf = 0; kf < 3; ++kf) {
            bf16x8 k0f = *(const bf16x8*)&Ks[lr][kf * 32 + kq * 8];
            bf16x8 k1f = *(const bf16x8*)&Ks[16 + lr][kf * 32 + kq * 8];
            sg00 = __builtin_amdgcn_mfma_f32_16x16x32_bf16(k0f, Qf[0][kf], sg00, 0, 0, 0);
            sg01 = __builtin_amdgcn_mfma_f32_16x16x32_bf16(k1f, Qf[0][kf], sg01, 0, 0, 0);
            sg10 = __builtin_amdgcn_mfma_f32_16x16x32_bf16(k0f, Qf[1][kf], sg10, 0, 0, 0);
            sg11 = __builtin_amdgcn_mfma_f32_16x16x32_bf16(k1f, Qf[1][kf], sg11, 0, 0, 0);
        }

        // ---- causal masks (skipped on interior tiles; wave-uniform branch) ----
        float e0[8], e1[8];
        const bool full = (k0 + 31 <= qw0) && (k0 + 31 < S_);
        if (full) {
            #pragma unroll
            for (int r = 0; r < 4; ++r) {
                e0[r] = sg00[r]; e0[4 + r] = sg01[r];
                e1[r] = sg10[r]; e1[4 + r] = sg11[r];
            }
        } else {
            #pragma unroll
            for (int r = 0; r < 4; ++r) {
                const int ka = k0 + 4 * kq + r;
                const int kb = ka + 16;
                e0[r]     = (ka <= myq0 && ka < S_) ? sg00[r] : -1e30f;
                e0[4 + r] = (kb <= myq0 && kb < S_) ? sg01[r] : -1e30f;
                e1[r]     = (ka <= myq1 && ka < S_) ? sg10[r] : -1e30f;
                e1[4 + r] = (kb <= myq1 && kb < S_) ? sg11[r] : -1e30f;
            }
        }

        // ---- online softmax (per frag) ----
        float m0s = e0[0], m1s = e1[0];
        #pragma unroll
        for (int i = 1; i < 8; ++i) { m0s = fmaxf(m0s, e0[i]); m1s = fmaxf(m1s, e1[i]); }
        m0s = fmaxf(m0s, __shfl_xor(m0s, 16, 64));
        m0s = fmaxf(m0s, __shfl_xor(m0s, 32, 64));
        m1s = fmaxf(m1s, __shfl_xor(m1s, 16, 64));
        m1s = fmaxf(m1s, __shfl_xor(m1s, 32, 64));
        const float nm0 = fmaxf(mr0, m0s), nm1 = fmaxf(mr1, m1s);
        const float rs0 = __expf(mr0 - nm0), rs1 = __expf(mr1 - nm1);
        mr0 = nm0; mr1 = nm1;
        float ls0 = 0.f, ls1 = 0.f;
        #pragma unroll
        for (int i = 0; i < 8; ++i) {
            e0[i] = __expf(e0[i] - nm0); ls0 += e0[i];
            e1[i] = __expf(e1[i] - nm1); ls1 += e1[i];
        }
        ls0 += __shfl_xor(ls0, 16, 64); ls0 += __shfl_xor(ls0, 32, 64);
        ls1 += __shfl_xor(ls1, 16, 64); ls1 += __shfl_xor(ls1, 32, 64);
        lr0_ = lr0_ * rs0 + ls0;
        lr1_ = lr1_ * rs1 + ls1;

        // ---- pack P ----
        ushort4 p;
        p.x = bf16bits(e0[0]); p.y = bf16bits(e0[1]); p.z = bf16bits(e0[2]); p.w = bf16bits(e0[3]);
        *(ushort4*)&Ps[w][lr][4 * kq] = p;
        p.x = bf16bits(e0[4]); p.y = bf16bits(e0[5]); p.z = bf16bits(e0[6]); p.w = bf16bits(e0[7]);
        *(ushort4*)&Ps[w][lr][16 + 4 * kq] = p;
        p.x = bf16bits(e1[0]); p.y = bf16bits(e1[1]); p.z = bf16bits(e1[2]); p.w = bf16bits(e1[3]);
        *(ushort4*)&Ps[w][16 + lr][4 * kq] = p;
        p.x = bf16bits(e1[4]); p.y = bf16bits(e1[5]); p.z = bf16bits(e1[6]); p.w = bf16bits(e1[7]);
        *(ushort4*)&Ps[w][16 + lr][16 + 4 * kq] = p;

        // ---- rescale Of: rows of Of[f] are queries 16f + 4kq + r ----
        float rf0[4], rf1[4];
        #pragma unroll
        for (int r = 0; r < 4; ++r) {
            rf0[r] = __shfl(rs0, 4 * kq + r, 16);
            rf1[r] = __shfl(rs1, 4 * kq + r, 16);
        }
        #pragma unroll
        for (int c = 0; c < 6; ++c)
            #pragma unroll
            for (int r = 0; r < 4; ++r) {
                Of[0][c][r] *= rf0[r];
                Of[1][c][r] *= rf1[r];
            }

        // ---- O += P V ----
        bf16x8 Pf0 = *(const bf16x8*)&Ps[w][lr][kq * 8];
        bf16x8 Pf1 = *(const bf16x8*)&Ps[w][16 + lr][kq * 8];
        #pragma unroll
        for (int c = 0; c < 6; ++c) {
            bf16x8 Vf = *(const bf16x8*)&Vs[16 * c + lr][kq * 8];
            Of[0][c] = __builtin_amdgcn_mfma_f32_16x16x32_bf16(Pf0, Vf, Of[0][c], 0, 0, 0);
            Of[1][c] = __builtin_amdgcn_mfma_f32_16x16x32_bf16(Pf1, Vf, Of[1][c], 0, 0, 0);
        }
    }

    // ---- epilogue ----
    const float iq0 = 1.0f / lr0_, iq1 = 1.0f / lr1_;
    float inv0[4], inv1[4];
    #pragma unroll
    for (int r = 0; r < 4; ++r) {
        inv0[r] = __shfl(iq0, 4 * kq + r, 16);
        inv1[r] = __shfl(iq1, 4 * kq + r, 16);
    }
    #pragma unroll
    for (int c = 0; c < 6; ++c) {
        const int dim = 16 * c + lr;
        if (dim >= DK_) continue;
        #pragma unroll
        for (int r = 0; r < 4; ++r) {
            const int q_a = qw0 + 4 * kq + r;
            const int q_b = qw0 + 16 + 4 * kq + r;
            if (q_a < S_)
                ab[(size_t)(b * S_ + q_a) * KP1 + h * DK_ + dim] =
                    __float2bfloat16(Of[0][c][r] * inv0[r]);
            if (q_b < S_)
                ab[(size_t)(b * S_ + q_b) * KP1 + h * DK_ + dim] =
                    __float2bfloat16(Of[1][c][r] * inv1[r]);
        }
    }
}

// ============================= launch =============================
extern "C" void kernel_launch(void* const* d_in, const int* in_sizes, int n_in,
                              void* d_out, int out_size, void* d_ws, size_t ws_size,
                              hipStream_t stream)
{
    const float* x    = (const float*)d_in[0];
    const float* Wq   = (const float*)d_in[2];
    const float* bq   = (const float*)d_in[3];
    const float* Wk   = (const float*)d_in[4];
    const float* bk   = (const float*)d_in[5];
    const float* Wv   = (const float*)d_in[6];
    const float* bv   = (const float*)d_in[7];
    const float* Wo   = (const float*)d_in[8];
    const float* bo   = (const float*)d_in[9];
    const float* W1   = (const float*)d_in[10];
    const float* b1   = (const float*)d_in[11];
    const float* W2   = (const float*)d_in[12];
    const float* b2   = (const float*)d_in[13];
    const float* W3   = (const float*)d_in[14];
    const float* b3   = (const float*)d_in[15];
    const float* ln1g = (const float*)d_in[16];
    const float* ln1b = (const float*)d_in[17];
    const float* ln2g = (const float*)d_in[18];
    const float* ln2b = (const float*)d_in[19];
    const float* rc   = (const float*)d_in[20];
    const float* rs   = (const float*)d_in[21];
    float* out = (float*)d_out;

    char* wsb = (char*)d_ws;
    size_t off = 0;
    auto nxt = [&](size_t bytes) -> char* {
        char* p = wsb + off; off += (bytes + 255) & ~(size_t)255; return p;
    };
    bf16*  x2   = (bf16*)nxt((size_t)MROWS * KP1 * 2);
    bf16*  qkv  = (bf16*)nxt((size_t)MROWS * KP2 * 2);   // also hb later (KP2 >= QKVN)
    float* x1f  = (float*)nxt((size_t)MROWS * D_ * 4);   // Vt first, then x1
    bf16*  ab   = (bf16*)nxt((size_t)MROWS * KP1 * 2);
    bf16*  WqkvT= (bf16*)nxt((size_t)QKVN * KP1 * 2);
    bf16*  WoT  = (bf16*)nxt((size_t)D_ * KP1 * 2);
    bf16*  W1T  = (bf16*)nxt((size_t)FF_ * KP1 * 2);
    bf16*  W3T  = (bf16*)nxt((size_t)FF_ * KP1 * 2);
    bf16*  W2T  = (bf16*)nxt((size_t)D_ * KP2 * 2);
    bf16*  Qa   = (bf16*)nxt((size_t)B_ * H_ * SP * 96 * 2);
    bf16*  Ka   = (bf16*)nxt((size_t)B_ * H_ * SP * 96 * 2);
    float* bqkv = (float*)nxt((size_t)QKVN * 4);
    bf16*  Vt   = (bf16*)x1f;    // Vt dead before x1 is written (step 6)
    float* x1   = x1f;
    bf16*  hb   = qkv;           // qkv dead after vtrans; hb needs MROWS*KP2

    const dim3 blk(256);
    const dim3 gF(26, 82);       // x = N-tiles (fastest varying) -> round-0 M-major order
    const dim3 gD(9, 82);
    const int padN = MROWS * (KP1 - D_);

    zero_pads<<<(padN + 255) / 256, blk, 0, stream>>>(x2);
    zero_pads<<<(padN + 255) / 256, blk, 0, stream>>>(ab);
    bcat<<<(QKVN + 255) / 256, blk, 0, stream>>>(bq, bk, bv, bqkv);

    castT<<<dim3(34, 34),  blk, 0, stream>>>(Wq, WqkvT,                    D_, D_, KP1);
    castT<<<dim3(34, 34),  blk, 0, stream>>>(Wk, WqkvT + (size_t)D_ * KP1, D_, D_, KP1);
    castT<<<dim3(34, 34),  blk, 0, stream>>>(Wv, WqkvT + (size_t)2*D_*KP1, D_, D_, KP1);
    castT<<<dim3(34, 34),  blk, 0, stream>>>(Wo, WoT, D_, D_, KP1);
    castT<<<dim3(34, 102), blk, 0, stream>>>(W1, W1T, D_, FF_, KP1);
    castT<<<dim3(34, 102), blk, 0, stream>>>(W3, W3T, D_, FF_, KP1);
    castT<<<dim3(102, 34), blk, 0, stream>>>(W2, W2T, FF_, D_, KP2);

    // 1) LN1
    ln_kernel<<<MROWS, blk, 0, stream>>>(x, ln1g, ln1b, x2);
    // 2) merged QKV projection (bf16 out, row stride 3240)
    gemm_bf16<3><<<gF, blk, 0, stream>>>(x2, WqkvT, bqkv, nullptr, nullptr, qkv,
                                         MROWS, QKVN, KP1, QKVN, QKVN);
    // 3) RoPE + head layout
    rope_qk<<<dim3(SP, B_), blk, 0, stream>>>(qkv, rc, rs, Qa, Ka);
    // 4) V transpose
    vtrans<<<dim3(41, B_ * H_), blk, 0, stream>>>(qkv, Vt);
    // 5) MFMA flash attention -> ab  (128 queries/block -> 11 q-blocks)
    attn_mfma<<<dim3(11, B_ * H_), blk, 0, stream>>>(Qa, Ka, Vt, ab);
    // 6) O-proj + residual -> x1
    gemm_bf16<1><<<gD, blk, 0, stream>>>(ab, WoT, bo, x, x1, nullptr, MROWS, D_, KP1, D_, D_);
    // 7) LN2
    ln_kernel<<<MROWS, blk, 0, stream>>>(x1, ln2g, ln2b, x2);
    // 8) h1 = x2@W1 + b1
    gemm_bf16<3><<<gF, blk, 0, stream>>>(x2, W1T, b1, nullptr, nullptr, hb, MROWS, FF_, KP1, KP2, KP2);
    // 9) h = silu(h1)*(x2@W3 + b3)
    gemm_bf16<2><<<gF, blk, 0, stream>>>(x2, W3T, b3, nullptr, nullptr, hb, MROWS, FF_, KP1, KP2, KP2);
    // 10) out = x1 + h@W2 + b2
    gemm_bf16<1><<<gD, blk, 0, stream>>>(hb, W2T, b2, x1, out, nullptr, MROWS, D_, KP2, D_, D_);
}

// Round 7
// 1044.671 us; speedup vs baseline: 1.0778x; 1.0778x over previous
//
#include <hip/hip_runtime.h>
#include <hip/hip_bf16.h>
#include <cstdint>
#include <cstddef>

#define B_  8
#define S_  1300
#define D_  1080
#define H_  12
#define DK_ 90
#define FF_ 3240
#define MROWS (B_*S_)   // 10400
#define KP1 1088        // 1080 padded to /32
#define KP2 3264        // 3240 padded to /32
#define SP  1312        // S padded to /32 (41 K-tiles)
#define QKVN 3240       // 3*D
#define QSCALE 0.105409255338946f   // 1/sqrt(90)

typedef __hip_bfloat16 bf16;
typedef __bf16 bf16x8 __attribute__((ext_vector_type(8)));
typedef float  f32x4  __attribute__((ext_vector_type(4)));
typedef unsigned short u16x8 __attribute__((ext_vector_type(8)));
typedef unsigned int   u32x4 __attribute__((ext_vector_type(4)));

__device__ __forceinline__ void gload16(const void* g, void* l) {
    __builtin_amdgcn_global_load_lds((const __attribute__((address_space(1))) void*)g,
                                     (__attribute__((address_space(3))) void*)l, 16, 0, 0);
}
__device__ __forceinline__ unsigned short bf16bits(float f) {
    bf16 b = __float2bfloat16(f);
    return *(unsigned short*)&b;
}
// inline-asm LDS read: invisible to hipcc's waitcnt pass, so the outstanding
// global_load_lds ops are NOT auto-drained before it (the counted-vmcnt enabler).
// Rule 18: must be followed by s_waitcnt lgkmcnt(0) + sched_barrier(0) before use.
__device__ __forceinline__ bf16x8 dsr(unsigned byteaddr) {
    union { u32x4 u; bf16x8 b; } c;
    asm volatile("ds_read_b128 %0, %1" : "=&v"(c.u) : "v"(byteaddr));
    return c.b;
}

#define BAR()   __builtin_amdgcn_s_barrier()
#define LGKM0() asm volatile("s_waitcnt lgkmcnt(0)" ::: "memory")
#define SCB()   __builtin_amdgcn_sched_barrier(0)

// ================== zero pad columns [D_, KP1) of bf16 [MROWS, KP1] ==================
__global__ __launch_bounds__(256) void zero_pads(bf16* __restrict__ buf)
{
    const int idx = blockIdx.x * 256 + threadIdx.x;
    if (idx >= MROWS * (KP1 - D_)) return;
    const int row = idx >> 3, col = D_ + (idx & 7);
    buf[(size_t)row * KP1 + col] = __float2bfloat16(0.f);
}

// ================== concat qkv bias ==================
__global__ __launch_bounds__(256) void bcat(const float* __restrict__ bq,
    const float* __restrict__ bk, const float* __restrict__ bv,
    float* __restrict__ bqkv)
{
    const int i = blockIdx.x * 256 + threadIdx.x;
    if (i >= QKVN) return;
    bqkv[i] = (i < D_) ? bq[i] : (i < 2 * D_) ? bk[i - D_] : bv[i - 2 * D_];
}

// ===================== weight cast + transpose =====================
__global__ __launch_bounds__(256) void castT(const float* __restrict__ W,
    bf16* __restrict__ WT, int K, int N, int KP)
{
    __shared__ unsigned short t[32][33];
    const int tx = threadIdx.x & 31, ty = threadIdx.x >> 5;
    const int k0 = blockIdx.x * 32, n0 = blockIdx.y * 32;
    #pragma unroll
    for (int i = 0; i < 4; ++i) {
        const int k = k0 + ty + 8 * i;
        const int n = n0 + tx;
        float v = (k < K && n < N) ? W[(size_t)k * N + n] : 0.f;
        t[ty + 8 * i][tx] = bf16bits(v);
    }
    __syncthreads();
    #pragma unroll
    for (int i = 0; i < 4; ++i) {
        const int n = n0 + ty + 8 * i;
        const int kk = k0 + tx;
        if (n < N && kk < KP) *(unsigned short*)&WT[(size_t)n * KP + kk] = t[tx][ty + 8 * i];
    }
}

// ============================= LayerNorm =============================
__global__ __launch_bounds__(256) void ln_kernel(const float* __restrict__ x,
    const float* __restrict__ g, const float* __restrict__ b,
    bf16* __restrict__ y)
{
    __shared__ float xs[D_];
    __shared__ float red[8];
    const int row = blockIdx.x;
    const int tid = threadIdx.x;
    const float* xr = x + (size_t)row * D_;

    float s = 0.f, sq = 0.f;
    for (int d = tid; d < D_; d += 256) {
        float v = xr[d];
        xs[d] = v;
        s += v; sq += v * v;
    }
    #pragma unroll
    for (int off = 32; off > 0; off >>= 1) {
        s  += __shfl_down(s,  off, 64);
        sq += __shfl_down(sq, off, 64);
    }
    const int wave = tid >> 6, lane = tid & 63;
    if (lane == 0) { red[wave] = s; red[4 + wave] = sq; }
    __syncthreads();
    if (tid == 0) {
        float ts = 0.f, tq = 0.f;
        #pragma unroll
        for (int w = 0; w < 4; ++w) { ts += red[w]; tq += red[4 + w]; }
        red[0] = ts; red[4] = tq;
    }
    __syncthreads();
    const float mean = red[0] * (1.0f / D_);
    const float var  = red[4] * (1.0f / D_) - mean * mean;
    const float rstd = rsqrtf(var + 1e-5f);
    bf16* yr = y + (size_t)row * KP1;
    for (int d = tid; d < D_; d += 256)
        yr[d] = __float2bfloat16((xs[d] - mean) * rstd * g[d] + b[d]);
}

// ============================= bf16 MFMA GEMM (128x128, counted-vmcnt 3-slot ring) =============================
// (unchanged - verified: all GEMMs below attn's 181 us)
template<int MODE>
__global__ __launch_bounds__(256, 3) void gemm_bf16(
    const bf16* __restrict__ A, const bf16* __restrict__ BT,
    const float* __restrict__ bias, const float* __restrict__ res,
    float* __restrict__ Cf, bf16* __restrict__ Cb,
    int M, int N, int KP, int LDC, int NP)
{
    __shared__ unsigned short lds[24576];   // 48 KB: A slots [0,12288), B slots [12288,24576)

    const int tid = threadIdx.x;
    const int w = tid >> 6, l = tid & 63;
    const int lr = l & 15, kq = l >> 4;
    const int m0 = blockIdx.y * 128, n0 = blockIdx.x * 128;

    const int rs = w * 16 + (l >> 2);
    const int sx = ((l & 3) ^ ((l >> 3) & 3)) * 8;   // shorts
    const int ar0 = min(m0 + rs,      M - 1);
    const int ar1 = min(m0 + rs + 64, M - 1);
    const int br0 = min(n0 + rs,      N - 1);
    const int br1 = min(n0 + rs + 64, N - 1);
    const bf16* pa0 = A  + (size_t)ar0 * KP + sx;
    const bf16* pa1 = A  + (size_t)ar1 * KP + sx;
    const bf16* pb0 = BT + (size_t)br0 * KP + sx;
    const bf16* pb1 = BT + (size_t)br1 * KP + sx;

    const int wm = (w >> 1) * 64, wn = (w & 1) * 64;

    const unsigned ldsb = (unsigned)(size_t)(const __attribute__((address_space(3))) void*)&lds[0];
    const unsigned co = (unsigned)((kq ^ ((lr >> 1) & 3)) << 4);   // bytes
    unsigned aoffB[4], boffB[4];
    #pragma unroll
    for (int i = 0; i < 4; ++i) {
        aoffB[i] = ldsb + (unsigned)((wm + i * 16 + lr) * 64) + co;
        boffB[i] = ldsb + 24576u + (unsigned)((wn + i * 16 + lr) * 64) + co;
    }

    f32x4 acc[4][4] = {};
    const int nkt = KP >> 5;

#define STAGE(t, sl) do { \
    gload16(pa0 + (size_t)(t) * 32, &lds[(sl) * 4096 + w * 512]); \
    gload16(pa1 + (size_t)(t) * 32, &lds[(sl) * 4096 + 2048 + w * 512]); \
    gload16(pb0 + (size_t)(t) * 32, &lds[12288 + (sl) * 4096 + w * 512]); \
    gload16(pb1 + (size_t)(t) * 32, &lds[12288 + (sl) * 4096 + 2048 + w * 512]); \
} while (0)

    STAGE(0, 0);
    STAGE(1, 1);

    int sc_ = 0;
    int ss_ = 2;
    for (int t = 0; t < nkt; ++t) {
        if (t + 1 < nkt) { asm volatile("s_waitcnt vmcnt(4)" ::: "memory"); }
        else             { asm volatile("s_waitcnt vmcnt(0)" ::: "memory"); }
        BAR(); SCB();
        if (t + 2 < nkt) STAGE(t + 2, ss_);

        const unsigned sb = (unsigned)(sc_ * 8192);
        bf16x8 af[4], bv[4];
        #pragma unroll
        for (int i = 0; i < 4; ++i) af[i] = dsr(aoffB[i] + sb);
        #pragma unroll
        for (int j = 0; j < 4; ++j) bv[j] = dsr(boffB[j] + sb);
        LGKM0(); SCB();
        #pragma unroll
        for (int i = 0; i < 4; ++i)
            #pragma unroll
            for (int j = 0; j < 4; ++j)
                acc[i][j] = __builtin_amdgcn_mfma_f32_16x16x32_bf16(af[i], bv[j], acc[i][j], 0, 0, 0);
        SCB();

        sc_ = (sc_ == 2) ? 0 : sc_ + 1;
        ss_ = (ss_ == 2) ? 0 : ss_ + 1;
    }
#undef STAGE

    // ===== epilogue =====
    #pragma unroll
    for (int j = 0; j < 4; ++j) {
        const int n = n0 + wn + j * 16 + lr;
        if (n >= NP) continue;
        const bool real = (n < N);
        const float bn = real ? bias[n] : 0.f;
        #pragma unroll
        for (int i = 0; i < 4; ++i) {
            const int rowb = m0 + wm + i * 16 + kq * 4;
            #pragma unroll
            for (int r = 0; r < 4; ++r) {
                const int m = rowb + r;
                if (m < M) {
                    const size_t off = (size_t)m * LDC + n;
                    float val = acc[i][j][r] + bn;
                    if (MODE == 0) Cf[off] = val;
                    if (MODE == 1) Cf[off] = val + res[off];
                    if (MODE == 3) Cb[off] = real ? __float2bfloat16(val) : __float2bfloat16(0.f);
                    if (MODE == 2) {
                        if (real) {
                            const float prev = __bfloat162float(Cb[off]);
                            const float sig  = 1.0f / (1.0f + __expf(-prev));
                            Cb[off] = __float2bfloat16(prev * sig * val);
                        } else {
                            Cb[off] = __float2bfloat16(0.f);
                        }
                    }
                }
            }
        }
    }
}

// ============================= RoPE + head layout (bf16 qkv -> bf16 Qa/Ka) =============================
__global__ __launch_bounds__(256) void rope_qk(const bf16* __restrict__ qkv,
    const float* __restrict__ cosb, const float* __restrict__ sinb,
    bf16* __restrict__ Qa, bf16* __restrict__ Ka)
{
    const int s = blockIdx.x;       // 0..SP-1
    const int b = blockIdx.y;
    const int tid = threadIdx.x;

    if (s >= S_) {
        for (int idx = tid; idx < H_ * 96; idx += 256) {
            const int h = idx / 96, c = idx - (idx / 96) * 96;
            const size_t o = ((size_t)(b * H_ + h) * SP + s) * 96 + c;
            Qa[o] = __float2bfloat16(0.f);
            Ka[o] = __float2bfloat16(0.f);
        }
        return;
    }

    const bf16* row = qkv + (size_t)(b * S_ + s) * QKVN;

    for (int idx = tid; idx < H_ * 45; idx += 256) {
        const int h = idx / 45, d = idx - (idx / 45) * 45;
        const float c1 = cosb[s * DK_ + d],      s1 = sinb[s * DK_ + d];
        const float c2 = cosb[s * DK_ + d + 45], s2 = sinb[s * DK_ + d + 45];
        const size_t o = ((size_t)(b * H_ + h) * SP + s) * 96;
        const float q1 = __bfloat162float(row[h * DK_ + d]);
        const float q2 = __bfloat162float(row[h * DK_ + d + 45]);
        Qa[o + d]      = __float2bfloat16((q1 * c1 - q2 * s1) * QSCALE);
        Qa[o + d + 45] = __float2bfloat16((q2 * c2 + q1 * s2) * QSCALE);
        const float k1 = __bfloat162float(row[D_ + h * DK_ + d]);
        const float k2 = __bfloat162float(row[D_ + h * DK_ + d + 45]);
        Ka[o + d]      = __float2bfloat16(k1 * c1 - k2 * s1);
        Ka[o + d + 45] = __float2bfloat16(k2 * c2 + k1 * s2);
    }
    for (int idx = tid; idx < H_ * 6; idx += 256) {
        const int h = idx / 6, c = 90 + (idx - (idx / 6) * 6);
        const size_t o = ((size_t)(b * H_ + h) * SP + s) * 96 + c;
        Qa[o] = __float2bfloat16(0.f);
        Ka[o] = __float2bfloat16(0.f);
    }
}

// ============================= V transpose (bf16 qkv -> bf16 Vt) =============================
// v section of qkv -> Vt bf16 [B*H][96][SP]
__global__ __launch_bounds__(256) void vtrans(const bf16* __restrict__ qkv,
    bf16* __restrict__ Vt)
{
    __shared__ float T[96][33];
    const int k0 = blockIdx.x * 32;
    const int bh = blockIdx.y;
    const int b = bh / H_, h = bh % H_;
    const int tid = threadIdx.x;

    for (int idx = tid; idx < 32 * 90; idx += 256) {
        const int r = idx / 90, d = idx - (idx / 90) * 90;
        const int s = k0 + r;
        T[d][r] = (s < S_) ?
            __bfloat162float(qkv[(size_t)(b * S_ + s) * QKVN + 2 * D_ + h * DK_ + d]) : 0.f;
    }
    for (int idx = tid; idx < 32 * 6; idx += 256) {
        const int r = idx / 6, d = 90 + (idx - (idx / 6) * 6);
        T[d][r] = 0.f;
    }
    __syncthreads();
    for (int idx = tid; idx < 96 * 4; idx += 256) {
        const int d = idx >> 2, kk = (idx & 3) * 8;
        u16x8 v;
        #pragma unroll
        for (int i = 0; i < 8; ++i) v[i] = bf16bits(T[d][kk + i]);
        *(u16x8*)(Vt + ((size_t)bh * 96 + d) * SP + k0 + kk) = v;
    }
}

// ============================= MFMA flash attention (64 q/block + T14 async-stage) =============================
// grid (21, B*H), 256 thr = 4 waves — round-5 structure (verified 181 us, occupancy 27%).
// T14: each thread owns 3 fixed 16B chunks of the K/V tile. Loads for tile t+1 are
// ISSUED right after tile t's LDS-ready barrier (pinned by sched_barrier, before the
// causal skip so every wave prefetches); the ds_write lands at tile t+1's top, so the
// global latency hides under tile t's QK^T/softmax/PV instead of sitting on the
// critical path between barriers.
__global__ __launch_bounds__(256) void attn_mfma(const bf16* __restrict__ Qa,
    const bf16* __restrict__ Ka, const bf16* __restrict__ Vt,
    bf16* __restrict__ ab)
{
    __shared__ unsigned short Qs[64][104];   // 13312 B
    __shared__ unsigned short Ks[32][104];   //  6656 B
    __shared__ unsigned short Vs[96][40];    //  7680 B
    __shared__ unsigned short Ps[4][16][40]; //  5120 B

    const int tid = threadIdx.x;
    const int w = tid >> 6, l = tid & 63;
    const int lr = l & 15, kq = l >> 4;
    const int qblk = (int)gridDim.x - 1 - (int)blockIdx.x;   // big blocks first
    const int q0 = qblk * 64;
    const int bh = blockIdx.y;
    const int b = bh / H_, h = bh % H_;

    const bf16* Qg = Qa + (size_t)bh * SP * 96;
    const bf16* Kg = Ka + (size_t)bh * SP * 96;
    const bf16* Vg = Vt + (size_t)bh * 96 * SP;

    // ---- stage Q (64 rows x 96 cols) ----
    for (int c = tid; c < 768; c += 256) {
        const int row = c / 12, cc = c - row * 12;
        const int rg = q0 + row;
        u16x8 v = (u16x8)0;
        if (rg < SP) v = *(const u16x8*)(Qg + (size_t)rg * 96 + cc * 8);
        *(u16x8*)&Qs[row][cc * 8] = v;
    }
    __syncthreads();

    bf16x8 Qf[3];
    #pragma unroll
    for (int kf = 0; kf < 3; ++kf)
        Qf[kf] = *(const bf16x8*)&Qs[w * 16 + lr][kf * 32 + kq * 8];

    const int qw0 = q0 + w * 16;
    const int myq = qw0 + lr;                       // this thread's query
    const int wlq = (qw0 < S_) ? min(qw0 + 15, S_ - 1) : -1;
    const int lastq = min(q0 + 63, S_ - 1);
    const int ntiles = lastq / 32 + 1;

    // ---- T14 staging slots: K tile = chunks 0..383 (row=c/12,col8=c%12),
    //      V tile = chunks 0..383 (d=c>>2, kk=(c&3)*8). Thread covers {tid, tid+256, tid+512}.
    const int r0 = tid / 12, c0 = tid - r0 * 12;          // K chunk tid
    const int c1k = tid + 256;
    const int r1 = c1k / 12, c1 = c1k - r1 * 12;          // K chunk (tid<128)
    const int v1 = tid - 128, d1 = (v1 >> 2) & 31, kk1 = (v1 & 3) * 8;  // V chunk (tid>=128)
    const int v2 = tid + 128, d2 = v2 >> 2, kk2 = (v2 & 3) * 8;         // V chunk
    const bool loK = (tid < 128);                          // wave-uniform (waves 0,1)

    const bf16* pK0 = Kg + r0 * 96 + c0 * 8;
    const bf16* pK1 = Kg + r1 * 96 + c1 * 8;
    const bf16* pV1 = Vg + (size_t)d1 * SP + kk1;
    const bf16* pV2 = Vg + (size_t)d2 * SP + kk2;

    u16x8 pf0, pf1, pf2;
    pf0 = *(const u16x8*)(pK0);
    pf1 = loK ? *(const u16x8*)(pK1) : *(const u16x8*)(pV1);
    pf2 = *(const u16x8*)(pV2);

    f32x4 Of[6] = {};
    float mrun = -1e30f, lrun = 0.f;                // per-query (lr), replicated over kq

    for (int kt = 0; kt < ntiles; ++kt) {
        const int k0 = kt * 32;
        __syncthreads();                            // prev tile's LDS reads done
        // ---- write prefetched tile to LDS ----
        *(u16x8*)&Ks[r0][c0 * 8] = pf0;
        if (loK) *(u16x8*)&Ks[r1][c1 * 8] = pf1;
        else     *(u16x8*)&Vs[d1][kk1]    = pf1;
        *(u16x8*)&Vs[d2][kk2] = pf2;
        __syncthreads();                            // tile kt ready
        // ---- issue prefetch for tile kt+1 (before causal skip; pinned here) ----
        if (kt + 1 < ntiles) {
            const int kn = k0 + 32;
            pf0 = *(const u16x8*)(pK0 + kn * 96);
            pf1 = loK ? *(const u16x8*)(pK1 + kn * 96) : *(const u16x8*)(pV1 + kn);
            pf2 = *(const u16x8*)(pV2 + kn);
        }
        SCB();                                      // keep loads issued above compute

        if (k0 > wlq) continue;   // wave-uniform skip; barriers above still executed

        // ---- S^T = K Q^T : thread holds keys {k0+16g+4kq+r} for query myq ----
        f32x4 sg0 = {0.f, 0.f, 0.f, 0.f}, sg1 = {0.f, 0.f, 0.f, 0.f};
        #pragma unroll
        for (int kf = 0; kf < 3; ++kf) {
            bf16x8 k0f = *(const bf16x8*)&Ks[lr][kf * 32 + kq * 8];
            bf16x8 k1f = *(const bf16x8*)&Ks[16 + lr][kf * 32 + kq * 8];
            sg0 = __builtin_amdgcn_mfma_f32_16x16x32_bf16(k0f, Qf[kf], sg0, 0, 0, 0);
            sg1 = __builtin_amdgcn_mfma_f32_16x16x32_bf16(k1f, Qf[kf], sg1, 0, 0, 0);
        }

        // ---- online softmax over keys ----
        float e[8];
        float msub = -1e30f;
        #pragma unroll
        for (int r = 0; r < 4; ++r) {
            const int ka = k0 + 4 * kq + r;
            const int kb = ka + 16;
            const float a = (ka <= myq && ka < S_) ? sg0[r] : -1e30f;
            const float c = (kb <= myq && kb < S_) ? sg1[r] : -1e30f;
            e[r] = a; e[4 + r] = c;
            msub = fmaxf(msub, fmaxf(a, c));
        }
        msub = fmaxf(msub, __shfl_xor(msub, 16, 64));
        msub = fmaxf(msub, __shfl_xor(msub, 32, 64));
        const float nm = fmaxf(mrun, msub);
        const float resc = __expf(mrun - nm);
        mrun = nm;
        float ls = 0.f;
        #pragma unroll
        for (int i = 0; i < 8; ++i) {
            const float ev = (e[i] > -1e29f) ? __expf(e[i] - nm) : 0.f;
            e[i] = ev; ls += ev;
        }
        ls += __shfl_xor(ls, 16, 64);
        ls += __shfl_xor(ls, 32, 64);
        lrun = lrun * resc + ls;

        // ---- pack P (query=lr row, keys 4kq..4kq+3 and +16) ----
        ushort4 p0, p1;
        p0.x = bf16bits(e[0]); p0.y = bf16bits(e[1]); p0.z = bf16bits(e[2]); p0.w = bf16bits(e[3]);
        p1.x = bf16bits(e[4]); p1.y = bf16bits(e[5]); p1.z = bf16bits(e[6]); p1.w = bf16bits(e[7]);
        *(ushort4*)&Ps[w][lr][4 * kq]      = p0;
        *(ushort4*)&Ps[w][lr][16 + 4 * kq] = p1;

        // ---- rescale Of ----
        float rf[4];
        #pragma unroll
        for (int r = 0; r < 4; ++r) rf[r] = __shfl(resc, 4 * kq + r, 16);
        #pragma unroll
        for (int c = 0; c < 6; ++c)
            #pragma unroll
            for (int r = 0; r < 4; ++r)
                Of[c][r] *= rf[r];

        // ---- O += P V ----
        bf16x8 Pf = *(const bf16x8*)&Ps[w][lr][kq * 8];
        #pragma unroll
        for (int c = 0; c < 6; ++c) {
            bf16x8 Vf = *(const bf16x8*)&Vs[16 * c + lr][kq * 8];
            Of[c] = __builtin_amdgcn_mfma_f32_16x16x32_bf16(Pf, Vf, Of[c], 0, 0, 0);
        }
    }

    // ---- epilogue ----
    const float invq = 1.0f / lrun;      // indexed by lr
    float inv[4];
    #pragma unroll
    for (int r = 0; r < 4; ++r) inv[r] = __shfl(invq, 4 * kq + r, 16);
    #pragma unroll
    for (int c = 0; c < 6; ++c) {
        const int dim = 16 * c + lr;
        if (dim >= DK_) continue;
        #pragma unroll
        for (int r = 0; r < 4; ++r) {
            const int qrow = qw0 + 4 * kq + r;
            if (qrow < S_)
                ab[(size_t)(b * S_ + qrow) * KP1 + h * DK_ + dim] =
                    __float2bfloat16(Of[c][r] * inv[r]);
        }
    }
}

// ============================= launch =============================
extern "C" void kernel_launch(void* const* d_in, const int* in_sizes, int n_in,
                              void* d_out, int out_size, void* d_ws, size_t ws_size,
                              hipStream_t stream)
{
    const float* x    = (const float*)d_in[0];
    const float* Wq   = (const float*)d_in[2];
    const float* bq   = (const float*)d_in[3];
    const float* Wk   = (const float*)d_in[4];
    const float* bk   = (const float*)d_in[5];
    const float* Wv   = (const float*)d_in[6];
    const float* bv   = (const float*)d_in[7];
    const float* Wo   = (const float*)d_in[8];
    const float* bo   = (const float*)d_in[9];
    const float* W1   = (const float*)d_in[10];
    const float* b1   = (const float*)d_in[11];
    const float* W2   = (const float*)d_in[12];
    const float* b2   = (const float*)d_in[13];
    const float* W3   = (const float*)d_in[14];
    const float* b3   = (const float*)d_in[15];
    const float* ln1g = (const float*)d_in[16];
    const float* ln1b = (const float*)d_in[17];
    const float* ln2g = (const float*)d_in[18];
    const float* ln2b = (const float*)d_in[19];
    const float* rc   = (const float*)d_in[20];
    const float* rs   = (const float*)d_in[21];
    float* out = (float*)d_out;

    char* wsb = (char*)d_ws;
    size_t off = 0;
    auto nxt = [&](size_t bytes) -> char* {
        char* p = wsb + off; off += (bytes + 255) & ~(size_t)255; return p;
    };
    bf16*  x2   = (bf16*)nxt((size_t)MROWS * KP1 * 2);
    bf16*  qkv  = (bf16*)nxt((size_t)MROWS * KP2 * 2);   // also hb later (KP2 >= QKVN)
    float* x1f  = (float*)nxt((size_t)MROWS * D_ * 4);   // Vt first, then x1
    bf16*  ab   = (bf16*)nxt((size_t)MROWS * KP1 * 2);
    bf16*  WqkvT= (bf16*)nxt((size_t)QKVN * KP1 * 2);
    bf16*  WoT  = (bf16*)nxt((size_t)D_ * KP1 * 2);
    bf16*  W1T  = (bf16*)nxt((size_t)FF_ * KP1 * 2);
    bf16*  W3T  = (bf16*)nxt((size_t)FF_ * KP1 * 2);
    bf16*  W2T  = (bf16*)nxt((size_t)D_ * KP2 * 2);
    bf16*  Qa   = (bf16*)nxt((size_t)B_ * H_ * SP * 96 * 2);
    bf16*  Ka   = (bf16*)nxt((size_t)B_ * H_ * SP * 96 * 2);
    float* bqkv = (float*)nxt((size_t)QKVN * 4);
    bf16*  Vt   = (bf16*)x1f;    // Vt dead before x1 is written (step 6)
    float* x1   = x1f;
    bf16*  hb   = qkv;           // qkv dead after vtrans; hb needs MROWS*KP2

    const dim3 blk(256);
    const dim3 gF(26, 82);       // x = N-tiles (fastest varying) -> round-0 M-major order
    const dim3 gD(9, 82);
    const int padN = MROWS * (KP1 - D_);

    zero_pads<<<(padN + 255) / 256, blk, 0, stream>>>(x2);
    zero_pads<<<(padN + 255) / 256, blk, 0, stream>>>(ab);
    bcat<<<(QKVN + 255) / 256, blk, 0, stream>>>(bq, bk, bv, bqkv);

    castT<<<dim3(34, 34),  blk, 0, stream>>>(Wq, WqkvT,                    D_, D_, KP1);
    castT<<<dim3(34, 34),  blk, 0, stream>>>(Wk, WqkvT + (size_t)D_ * KP1, D_, D_, KP1);
    castT<<<dim3(34, 34),  blk, 0, stream>>>(Wv, WqkvT + (size_t)2*D_*KP1, D_, D_, KP1);
    castT<<<dim3(34, 34),  blk, 0, stream>>>(Wo, WoT, D_, D_, KP1);
    castT<<<dim3(34, 102), blk, 0, stream>>>(W1, W1T, D_, FF_, KP1);
    castT<<<dim3(34, 102), blk, 0, stream>>>(W3, W3T, D_, FF_, KP1);
    castT<<<dim3(102, 34), blk, 0, stream>>>(W2, W2T, FF_, D_, KP2);

    // 1) LN1
    ln_kernel<<<MROWS, blk, 0, stream>>>(x, ln1g, ln1b, x2);
    // 2) merged QKV projection (bf16 out, row stride 3240)
    gemm_bf16<3><<<gF, blk, 0, stream>>>(x2, WqkvT, bqkv, nullptr, nullptr, qkv,
                                         MROWS, QKVN, KP1, QKVN, QKVN);
    // 3) RoPE + head layout
    rope_qk<<<dim3(SP, B_), blk, 0, stream>>>(qkv, rc, rs, Qa, Ka);
    // 4) V transpose
    vtrans<<<dim3(41, B_ * H_), blk, 0, stream>>>(qkv, Vt);
    // 5) MFMA flash attention -> ab
    attn_mfma<<<dim3(21, B_ * H_), blk, 0, stream>>>(Qa, Ka, Vt, ab);
    // 6) O-proj + residual -> x1
    gemm_bf16<1><<<gD, blk, 0, stream>>>(ab, WoT, bo, x, x1, nullptr, MROWS, D_, KP1, D_, D_);
    // 7) LN2
    ln_kernel<<<MROWS, blk, 0, stream>>>(x1, ln2g, ln2b, x2);
    // 8) h1 = x2@W1 + b1
    gemm_bf16<3><<<gF, blk, 0, stream>>>(x2, W1T, b1, nullptr, nullptr, hb, MROWS, FF_, KP1, KP2, KP2);
    // 9) h = silu(h1)*(x2@W3 + b3)
    gemm_bf16<2><<<gF, blk, 0, stream>>>(x2, W3T, b3, nullptr, nullptr, hb, MROWS, FF_, KP1, KP2, KP2);
    // 10) out = x1 + h@W2 + b2
    gemm_bf16<1><<<gD, blk, 0, stream>>>(hb, W2T, b2, x1, out, nullptr, MROWS, D_, KP2, D_, D_);
}